// Round 6
// baseline (2297.421 us; speedup 1.0000x reference)
//
#include <hip/hip_runtime.h>
#include <math.h>

#define NPTS 2048
#define NB 8
#define R 4        // rows per thread
#define NW 16      // waves per block = column chunks
#define BROWS 256  // rows per block (64 lanes * R)
#define CPAIR 64   // col-pairs per wave chunk (128 cols)

typedef float v2f __attribute__((ext_vector_type(2)));

__device__ __forceinline__ float wexp2(float v) { return __builtin_amdgcn_exp2f(v); }
__device__ __forceinline__ v2f fma2(v2f a, v2f b, v2f c) {
  return __builtin_elementwise_fma(a, b, c);
}
__device__ __forceinline__ v2f max2(v2f a, v2f b) {
  return __builtin_elementwise_max(a, b);
}

// Forced packed fp32 math (CDNA2+ VOP3P). hipcc scalarizes ext_vector float2
// arithmetic (measured r5: VALUBusy-derived issue == scalar model), so emit
// v_pk_* directly.
__device__ __forceinline__ v2f pk_fma(v2f a, v2f b, v2f c) {
  v2f d;
  asm("v_pk_fma_f32 %0, %1, %2, %3" : "=v"(d) : "v"(a), "v"(b), "v"(c));
  return d;
}
__device__ __forceinline__ v2f pk_add(v2f a, v2f b) {
  v2f d;
  asm("v_pk_add_f32 %0, %1, %2" : "=v"(d) : "v"(a), "v"(b));
  return d;
}

// deg-4 Taylor of 2^f on [-0.5,0.5]; rel err ~4e-5 (validated r5: absmax 0.0)
#define EXP2_C1 0.6931471805599453f
#define EXP2_C2 0.2402265069591007f
#define EXP2_C3 0.05550410866482158f
#define EXP2_C4 0.009618129107628477f
// KRB = 1.5*2^23 + 127: range-reduction magic with exponent bias pre-added, so
// E = bits(y)<<23 directly (no +0x3F800000).  y = RNE(s + (KRB - m)) =
// RK + 127 + n, n = round(s-m).  EMINB = bits(RK+1) clamps n >= -126 on the
// integer side only (bits monotonic); f-path needs no clamp since n=round(d).
#define KRB 12583039.0f
#define EMINB 0x4B400001u

// ---------------------------------------------------------------------------
// init: packed point records (x,y,z, 0.5*|p|^2), zero potentials, zero output.
// ---------------------------------------------------------------------------
__global__ __launch_bounds__(256) void emd_init(const float* __restrict__ x,
                                                const float* __restrict__ y,
                                                float4* __restrict__ x4,
                                                float4* __restrict__ y4,
                                                float* __restrict__ pot0,
                                                float* __restrict__ out) {
  int t = blockIdx.x * blockDim.x + threadIdx.x;  // 0..65535
  if (t < NB * NPTS) {
    float a0 = x[3 * t], a1 = x[3 * t + 1], a2 = x[3 * t + 2];
    x4[t] = make_float4(a0, a1, a2, 0.5f * (a0 * a0 + a1 * a1 + a2 * a2));
    float b0 = y[3 * t], b1 = y[3 * t + 1], b2 = y[3 * t + 2];
    y4[t] = make_float4(b0, b1, b2, 0.5f * (b0 * b0 + b1 * b1 + b2 * b2));
  }
  pot0[t] = 0.0f;
  if (t == 0) out[0] = 0.0f;
}

// ---------------------------------------------------------------------------
// Shared geometry (round-2 skeleton, proven): 256 blocks x 1024 threads;
// block=(mat,b,256-row group); 16 waves = 128-col chunks; R=4 rows/thread;
// 1 block/CU (4 waves/SIMD, __launch_bounds__(1024,4) -> 128 VGPR cap).
// Column pair packed A=(x0,x1,y0,y1), B=(z0,z1,w0,w1), w=(h-0.5|q|^2)*c.
// ---------------------------------------------------------------------------

// Bootstrap sweep: exact online softmax (first eps only, HW exp2) + amax store.
__global__ __launch_bounds__(1024, 4) void emd_sweep_boot(
    const float4* __restrict__ x4, const float4* __restrict__ y4,
    const float* __restrict__ pot_in, float* __restrict__ pot_out,
    float* __restrict__ amax_out, float c, float neg_eps_ln2, float eps_logM) {
  __shared__ union {
    struct {
      float4 A[NPTS / 2];          // 16 KB
      float4 B[NPTS / 2];          // 16 KB
    } cp;
    struct {
      float m[NW][BROWS];          // 16 KB
      float l[NW][BROWS];          // 16 KB
    } mg;
  } sh;

  int blk = blockIdx.x;            // 0..255
  int mat = blk >> 6;
  int b = (blk >> 3) & 7;
  int rg = blk & 7;                // 256-row group
  int tid = threadIdx.x;
  int lane = tid & 63;
  int w = tid >> 6;                // 0..15

  const float4* rowp = (mat == 1 || mat == 3) ? y4 : x4;
  const float4* colp = (mat == 0 || mat == 3) ? y4 : x4;
  int hidx = (mat < 2) ? (mat ^ 1) : mat;
  const float* h = pot_in + (hidx * NB + b) * NPTS;
  const float4* colb = colp + b * NPTS;

  {
    float4 q0 = colb[2 * tid];
    float4 q1 = colb[2 * tid + 1];
    float2 hv = ((const float2*)h)[tid];
    sh.cp.A[tid] = make_float4(q0.x, q1.x, q0.y, q1.y);
    sh.cp.B[tid] = make_float4(q0.z, q1.z, (hv.x - q0.w) * c, (hv.y - q1.w) * c);
  }
  __syncthreads();

  int rowbase = rg * BROWS;
  const float4* rowb = rowp + b * NPTS + rowbase;

  v2f xs0[R], xs1[R], xs2[R];
  float m[R], l[R];
#pragma unroll
  for (int r = 0; r < R; ++r) {
    float4 p = rowb[r * 64 + lane];
    float a0 = p.x * c, a1 = p.y * c, a2 = p.z * c;
    xs0[r] = (v2f){a0, a0};
    xs1[r] = (v2f){a1, a1};
    xs2[r] = (v2f){a2, a2};
    m[r] = -INFINITY;
    l[r] = 0.0f;
  }

  int p0 = w * CPAIR;
  for (int tp = 0; tp < CPAIR; tp += 4) {
    float4 A[4], B[4];
#pragma unroll
    for (int j = 0; j < 4; ++j) {
      A[j] = sh.cp.A[p0 + tp + j];
      B[j] = sh.cp.B[p0 + tp + j];
    }
#pragma unroll
    for (int r = 0; r < R; ++r) {
      v2f s2[4];
#pragma unroll
      for (int j = 0; j < 4; ++j) {
        v2f qx = {A[j].x, A[j].y};
        v2f qy = {A[j].z, A[j].w};
        v2f qz = {B[j].x, B[j].y};
        v2f qw = {B[j].z, B[j].w};
        s2[j] = fma2(xs0[r], qx, fma2(xs1[r], qy, fma2(xs2[r], qz, qw)));
      }
      v2f t0 = max2(s2[0], s2[1]);
      v2f t1 = max2(s2[2], s2[3]);
      v2f u = max2(t0, t1);
      float mt = fmaxf(u.x, u.y);
      float mn = fmaxf(m[r], mt);
      v2f mn2 = {mn, mn};
      v2f acc = {0.0f, 0.0f};
#pragma unroll
      for (int j = 0; j < 4; ++j) {
        v2f d = s2[j] - mn2;
        v2f e;
        e.x = wexp2(d.x);
        e.y = wexp2(d.y);
        acc += e;
      }
      float er = wexp2(m[r] - mn);
      l[r] = fmaf(l[r], er, acc.x + acc.y);
      m[r] = mn;
    }
  }

  __syncthreads();
#pragma unroll
  for (int r = 0; r < R; ++r) {
    sh.mg.m[w][r * 64 + lane] = m[r];
    sh.mg.l[w][r * 64 + lane] = l[r];
  }
  __syncthreads();

  if (w < 4) {
    int row = w * 64 + lane;       // 0..255
    float M = sh.mg.m[0][row];
#pragma unroll
    for (int q = 1; q < NW; ++q) M = fmaxf(M, sh.mg.m[q][row]);
    float L = 0.0f;
#pragma unroll
    for (int q = 0; q < NW; ++q)
      L += sh.mg.l[q][row] * wexp2(sh.mg.m[q][row] - M);
    float pw = rowb[row].w;
    float res = pw + neg_eps_ln2 * (M + log2f(L)) + eps_logM;
    float invc = -neg_eps_ln2;     // = 1/c
    amax_out[(mat * NB + b) * NPTS + rowbase + row] = M * invc;
    const float* oldp = pot_in + (mat * NB + b) * NPTS + rowbase;
    float* outp = pot_out + (mat * NB + b) * NPTS + rowbase;
    outp[row] = 0.5f * (oldp[row] + res);
  }
}

// Fixed-reference sweep: exp2(s - Mref) via forced-packed VALU polynomial.
// Per 2-element chain: 10 v_pk ops + 2 u32 max + 2 shl + 2 scalar fma; no
// trans-pipe ops. kr = KRB - Mref folds range reduction + exponent bias.
// Clamped lanes (d < -126) contribute 2^-126 * p(f) ~ 0: exact no-op.
// Merge uses m_eff = KRB - kr (Sterbenz-exact) so lse matches the kernel's
// actual reference.
template <bool FINAL>
__global__ __launch_bounds__(1024, 4) void emd_sweep_ref(
    const float4* __restrict__ x4, const float4* __restrict__ y4,
    const float* __restrict__ pot_in, float* __restrict__ pot_out,
    const float* __restrict__ amax_in, float* __restrict__ amax_out,
    float* __restrict__ out, float c, float neg_eps_ln2, float eps_logM) {
  __shared__ union {
    struct {
      float4 A[NPTS / 2];          // 16 KB
      float4 B[NPTS / 2];          // 16 KB
    } cp;
    float lbuf[NW][BROWS];         // merge phase (colpack dead), 16 KB
  } sh;

  int blk = blockIdx.x;            // 0..255
  int mat = blk >> 6;
  int b = (blk >> 3) & 7;
  int rg = blk & 7;
  int tid = threadIdx.x;
  int lane = tid & 63;
  int w = tid >> 6;

  const float4* rowp = (mat == 1 || mat == 3) ? y4 : x4;
  const float4* colp = (mat == 0 || mat == 3) ? y4 : x4;
  int hidx = (mat < 2) ? (mat ^ 1) : mat;
  const float* h = pot_in + (hidx * NB + b) * NPTS;
  const float4* colb = colp + b * NPTS;

  {
    float4 q0 = colb[2 * tid];
    float4 q1 = colb[2 * tid + 1];
    float2 hv = ((const float2*)h)[tid];
    sh.cp.A[tid] = make_float4(q0.x, q1.x, q0.y, q1.y);
    sh.cp.B[tid] = make_float4(q0.z, q1.z, (hv.x - q0.w) * c, (hv.y - q1.w) * c);
  }

  int rowbase = rg * BROWS;
  const float4* rowb = rowp + b * NPTS + rowbase;
  const float* amrow = amax_in + (mat * NB + b) * NPTS + rowbase;

  v2f xs0[R], xs1[R], xs2[R], kr[R];
  float accx[R], accy[R];
#pragma unroll
  for (int r = 0; r < R; ++r) {
    float4 p = rowb[r * 64 + lane];
    float a0 = p.x * c, a1 = p.y * c, a2 = p.z * c;
    xs0[r] = (v2f){a0, a0};
    xs1[r] = (v2f){a1, a1};
    xs2[r] = (v2f){a2, a2};
    float mr = amrow[r * 64 + lane] * c;
    float krv = KRB - mr;
    kr[r] = (v2f){krv, krv};
    accx[r] = 0.0f;
    accy[r] = 0.0f;
  }
  __syncthreads();

  const v2f neg1 = {-1.0f, -1.0f};
  const v2f c4v = {EXP2_C4, EXP2_C4};
  const v2f c3v = {EXP2_C3, EXP2_C3};
  const v2f c2v = {EXP2_C2, EXP2_C2};
  const v2f c1v = {EXP2_C1, EXP2_C1};
  const v2f onev = {1.0f, 1.0f};

  int p0 = w * CPAIR;
  for (int tp = 0; tp < CPAIR; tp += 4) {   // 4 pairs = 8 cols per iter
    float4 A[4], B[4];
#pragma unroll
    for (int j = 0; j < 4; ++j) {
      A[j] = sh.cp.A[p0 + tp + j];
      B[j] = sh.cp.B[p0 + tp + j];
    }
#pragma unroll
    for (int r = 0; r < R; ++r) {
#pragma unroll
      for (int j = 0; j < 4; ++j) {
        v2f qx = {A[j].x, A[j].y};
        v2f qy = {A[j].z, A[j].w};
        v2f qz = {B[j].x, B[j].y};
        v2f qw = {B[j].z, B[j].w};
        v2f s2 = pk_fma(xs0[r], qx, pk_fma(xs1[r], qy, pk_fma(xs2[r], qz, qw)));
        v2f yv = pk_add(s2, kr[r]);               // RNE -> RK+127+n
        v2f uv = pk_fma(neg1, kr[r], yv);         // u = y - kr = n + m_eff
        v2f fv = pk_fma(neg1, uv, s2);            // f = s - u in [-0.5,0.5]
        v2f pv = pk_fma(fv, c4v, c3v);
        pv = pk_fma(fv, pv, c2v);
        pv = pk_fma(fv, pv, c1v);
        pv = pk_fma(fv, pv, onev);
        unsigned eux = __float_as_uint(yv.x);
        unsigned euy = __float_as_uint(yv.y);
        eux = eux < EMINB ? EMINB : eux;          // v_max_u32: n >= -126
        euy = euy < EMINB ? EMINB : euy;
        accx[r] = fmaf(pv.x, __uint_as_float(eux << 23), accx[r]);
        accy[r] = fmaf(pv.y, __uint_as_float(euy << 23), accy[r]);
      }
    }
  }

  __syncthreads();  // colpack dead; safe to overwrite (union)
#pragma unroll
  for (int r = 0; r < R; ++r)
    sh.lbuf[w][r * 64 + lane] = accx[r] + accy[r];
  __syncthreads();

  if (w < 4) {
    int row = w * 64 + lane;       // 0..255
    float L = sh.lbuf[0][row];
#pragma unroll
    for (int q = 1; q < NW; ++q) L += sh.lbuf[q][row];
    float mr = amrow[row] * c;
    float krv = KRB - mr;          // same fp computation as kernel body
    float meff = KRB - krv;        // Sterbenz-exact actual reference
    float lse = meff + log2f(L);
    float pw = rowb[row].w;
    float res = pw + neg_eps_ln2 * lse + eps_logM;
    float invc = -neg_eps_ln2;
    if (FINAL) {
      float sign = (mat < 2) ? 1.0f : -1.0f;
      float val = sign * res * (1.0f / (float)(NB * NPTS));
#pragma unroll
      for (int off = 32; off; off >>= 1) val += __shfl_xor(val, off);
      if (lane == 0) atomicAdd(out, val);
    } else {
      amax_out[(mat * NB + b) * NPTS + rowbase + row] = lse * invc;
      const float* oldp = pot_in + (mat * NB + b) * NPTS + rowbase;
      float* outp = pot_out + (mat * NB + b) * NPTS + rowbase;
      outp[row] = 0.5f * (oldp[row] + res);
    }
  }
}

// ---------------------------------------------------------------------------
extern "C" void kernel_launch(void* const* d_in, const int* in_sizes, int n_in,
                              void* d_out, int out_size, void* d_ws, size_t ws_size,
                              hipStream_t stream) {
  const float* x = (const float*)d_in[0];
  const float* y = (const float*)d_in[1];
  float* out = (float*)d_out;

  char* ws = (char*)d_ws;
  float4* x4 = (float4*)ws;                        // 256 KB
  float4* y4 = (float4*)(ws + 262144);             // 256 KB
  float* pot = (float*)(ws + 524288);              // 2 * 65536 floats = 512 KB
  float* amax = (float*)(ws + 1048576);            // 65536 floats = 256 KB

  emd_init<<<256, 256, 0, stream>>>(x, y, x4, y4, pot, out);

  // eps schedule: s=8.0, *=0.9 while s>0.01; eps = f32(s)^2; append 0.01^2
  float eps_arr[80];
  int ne = 0;
  double s = 8.0;
  while (s > 0.01) {
    float sf = (float)s;
    eps_arr[ne++] = sf * sf;
    s *= 0.9;
  }
  {
    float bf = 0.01f;
    eps_arr[ne++] = bf * bf;
  }

  const double LOG2E = 1.4426950408889634;
  const double LN2 = 0.6931471805599453;
  const double LOG2048 = 7.624618986159398;

  int cur = 0;
  for (int k = 0; k < ne; ++k) {
    float eps = eps_arr[k];
    float c = (float)(LOG2E / (double)eps);
    float nel = (float)(-(double)eps * LN2);
    float elM = (float)((double)eps * LOG2048);
    if (k == 0) {
      emd_sweep_boot<<<256, 1024, 0, stream>>>(x4, y4, pot + cur * 65536,
                                               pot + (1 - cur) * 65536, amax,
                                               c, nel, elM);
    } else {
      emd_sweep_ref<false><<<256, 1024, 0, stream>>>(
          x4, y4, pot + cur * 65536, pot + (1 - cur) * 65536, amax, amax, out,
          c, nel, elM);
    }
    cur ^= 1;
  }

  {
    float eps = eps_arr[ne - 1];
    float c = (float)(LOG2E / (double)eps);
    float nel = (float)(-(double)eps * LN2);
    float elM = (float)((double)eps * LOG2048);
    emd_sweep_ref<true><<<256, 1024, 0, stream>>>(
        x4, y4, pot + cur * 65536, nullptr, amax, nullptr, out, c, nel, elM);
  }
}

// Round 7
// 1403.943 us; speedup vs baseline: 1.6364x; 1.6364x over previous
//
#include <hip/hip_runtime.h>
#include <math.h>

// ---------------------------------------------------------------------------
// Session findings (rounds 0-6), kept as the record for this kernel:
//  - Per-sweep inner work: 134M elements x (3 fma + 1 sub + 1 acc-add + 1 exp2).
//    Issue model per v2f chain (2 elems, wave64): 10 VALU instr x 2 cyc +
//    2 x v_exp_f32 at ~12.7 cyc (trans issue-serializes with VALU; no overlap
//    observed at 8 waves/SIMD across 3 structures). Floor 45 cyc; this kernel
//    measures 49 (incl. ds_read + loop) = ~92% of floor, 20.9 us/sweep.
//  - r1 scalar-path (s_load streaming): 22.3 us/sweep (K$ serialization).
//  - r2 R=4 (half LDS broadcast traffic): 21.9 us/sweep -> NOT LDS-BW bound.
//  - r3/r4 exact tile culling: bounds carry O(1) slack vs 64/c keep-window;
//    pruned ~nothing, +prologue cost. Structurally dead for this data.
//  - r5/r6 polynomial exp2 (scalar and forced v_pk): 52 cyc/chain both ways —
//    fp32 pk ops are per-element-rate-equal to scalar on CDNA. Dead.
//  => This structure is the roofline for the algorithm as specified.
// ---------------------------------------------------------------------------

#define NPTS 2048
#define NB 8
#define R 2        // rows per thread
#define NW 16      // waves per block = column chunks
#define BROWS 128  // rows per block
#define CPAIR 64   // col-pairs per wave chunk (128 cols)

typedef float v2f __attribute__((ext_vector_type(2)));

__device__ __forceinline__ float wexp2(float v) { return __builtin_amdgcn_exp2f(v); }
__device__ __forceinline__ v2f fma2(v2f a, v2f b, v2f c) {
  return __builtin_elementwise_fma(a, b, c);
}
__device__ __forceinline__ v2f max2(v2f a, v2f b) {
  return __builtin_elementwise_max(a, b);
}

// ---------------------------------------------------------------------------
// init: packed point records (x,y,z, 0.5*|p|^2), zero potentials, zero output.
// ---------------------------------------------------------------------------
__global__ __launch_bounds__(256) void emd_init(const float* __restrict__ x,
                                                const float* __restrict__ y,
                                                float4* __restrict__ x4,
                                                float4* __restrict__ y4,
                                                float* __restrict__ pot0,
                                                float* __restrict__ out) {
  int t = blockIdx.x * blockDim.x + threadIdx.x;  // 0..65535
  if (t < NB * NPTS) {
    float a0 = x[3 * t], a1 = x[3 * t + 1], a2 = x[3 * t + 2];
    x4[t] = make_float4(a0, a1, a2, 0.5f * (a0 * a0 + a1 * a1 + a2 * a2));
    float b0 = y[3 * t], b1 = y[3 * t + 1], b2 = y[3 * t + 2];
    y4[t] = make_float4(b0, b1, b2, 0.5f * (b0 * b0 + b1 * b1 + b2 * b2));
  }
  pot0[t] = 0.0f;
  if (t == 0) out[0] = 0.0f;
}

// ---------------------------------------------------------------------------
// Shared geometry: 512 blocks x 1024 threads; block=(mat,b,128-row group);
// 16 waves = column chunks of 128 cols (64 pairs); R=2 rows/thread.
// 2 blocks/CU co-resident -> 8 waves/SIMD, interleaved barrier domains.
// Column pair packed A=(x0,x1,y0,y1), B=(z0,z1,w0,w1), w=(h-0.5|y|^2)*c.
// ---------------------------------------------------------------------------

// Bootstrap sweep: exact online softmax (first eps only) + amax store.
__global__ __launch_bounds__(1024, 8) void emd_sweep_boot(
    const float4* __restrict__ x4, const float4* __restrict__ y4,
    const float* __restrict__ pot_in, float* __restrict__ pot_out,
    float* __restrict__ amax_out, float c, float neg_eps_ln2, float eps_logM) {
  __shared__ union {
    struct {
      float4 A[NPTS / 2];
      float4 B[NPTS / 2];
    } cp;
    struct {
      float m[NW][BROWS];
      float l[NW][BROWS];
    } mg;
  } sh;

  int blk = blockIdx.x;            // 0..511
  int mat = blk >> 7;
  int b = (blk >> 4) & 7;
  int rg = blk & 15;               // 128-row group
  int tid = threadIdx.x;
  int lane = tid & 63;
  int w = tid >> 6;                // 0..15

  const float4* rowp = (mat == 1 || mat == 3) ? y4 : x4;
  const float4* colp = (mat == 0 || mat == 3) ? y4 : x4;
  int hidx = (mat < 2) ? (mat ^ 1) : mat;
  const float* h = pot_in + (hidx * NB + b) * NPTS;
  const float4* colb = colp + b * NPTS;

  {
    float4 q0 = colb[2 * tid];
    float4 q1 = colb[2 * tid + 1];
    float2 hv = ((const float2*)h)[tid];
    sh.cp.A[tid] = make_float4(q0.x, q1.x, q0.y, q1.y);
    sh.cp.B[tid] = make_float4(q0.z, q1.z, (hv.x - q0.w) * c, (hv.y - q1.w) * c);
  }
  __syncthreads();

  int rowbase = rg * BROWS;
  const float4* rowb = rowp + b * NPTS + rowbase;

  v2f xs0[R], xs1[R], xs2[R];
  float m[R], l[R];
#pragma unroll
  for (int r = 0; r < R; ++r) {
    float4 p = rowb[r * 64 + lane];
    float a0 = p.x * c, a1 = p.y * c, a2 = p.z * c;
    xs0[r] = (v2f){a0, a0};
    xs1[r] = (v2f){a1, a1};
    xs2[r] = (v2f){a2, a2};
    m[r] = -INFINITY;
    l[r] = 0.0f;
  }

  int p0 = w * CPAIR;
  for (int tp = 0; tp < CPAIR; tp += 4) {
    float4 A[4], B[4];
#pragma unroll
    for (int j = 0; j < 4; ++j) {
      A[j] = sh.cp.A[p0 + tp + j];
      B[j] = sh.cp.B[p0 + tp + j];
    }
#pragma unroll
    for (int r = 0; r < R; ++r) {
      v2f s2[4];
#pragma unroll
      for (int j = 0; j < 4; ++j) {
        v2f qx = {A[j].x, A[j].y};
        v2f qy = {A[j].z, A[j].w};
        v2f qz = {B[j].x, B[j].y};
        v2f qw = {B[j].z, B[j].w};
        s2[j] = fma2(xs0[r], qx, fma2(xs1[r], qy, fma2(xs2[r], qz, qw)));
      }
      v2f t0 = max2(s2[0], s2[1]);
      v2f t1 = max2(s2[2], s2[3]);
      v2f u = max2(t0, t1);
      float mt = fmaxf(u.x, u.y);
      float mn = fmaxf(m[r], mt);
      v2f mn2 = {mn, mn};
      v2f acc = {0.0f, 0.0f};
#pragma unroll
      for (int j = 0; j < 4; ++j) {
        v2f d = s2[j] - mn2;
        v2f e;
        e.x = wexp2(d.x);
        e.y = wexp2(d.y);
        acc += e;
      }
      float er = wexp2(m[r] - mn);
      l[r] = fmaf(l[r], er, acc.x + acc.y);
      m[r] = mn;
    }
  }

  __syncthreads();
#pragma unroll
  for (int r = 0; r < R; ++r) {
    sh.mg.m[w][r * 64 + lane] = m[r];
    sh.mg.l[w][r * 64 + lane] = l[r];
  }
  __syncthreads();

  if (w < 2) {
    int row = w * 64 + lane;       // 0..127
    float M = sh.mg.m[0][row];
#pragma unroll
    for (int q = 1; q < NW; ++q) M = fmaxf(M, sh.mg.m[q][row]);
    float L = 0.0f;
#pragma unroll
    for (int q = 0; q < NW; ++q)
      L += sh.mg.l[q][row] * wexp2(sh.mg.m[q][row] - M);
    float pw = rowb[row].w;
    float res = pw + neg_eps_ln2 * (M + log2f(L)) + eps_logM;
    float invc = -neg_eps_ln2;     // = 1/c
    amax_out[(mat * NB + b) * NPTS + rowbase + row] = M * invc;
    const float* oldp = pot_in + (mat * NB + b) * NPTS + rowbase;
    float* outp = pot_out + (mat * NB + b) * NPTS + rowbase;
    outp[row] = 0.5f * (oldp[row] + res);
  }
}

// Fixed-reference sweep: exp2(s - Mref), Mref = amax_in[row]*c. Exact LSE;
// amax_out = (Mref + log2 L)/c self-corrects (always within +11 of true max).
template <bool FINAL>
__global__ __launch_bounds__(1024, 8) void emd_sweep_ref(
    const float4* __restrict__ x4, const float4* __restrict__ y4,
    const float* __restrict__ pot_in, float* __restrict__ pot_out,
    const float* __restrict__ amax_in, float* __restrict__ amax_out,
    float* __restrict__ out, float c, float neg_eps_ln2, float eps_logM) {
  __shared__ union {
    struct {
      float4 A[NPTS / 2];          // 16 KB
      float4 B[NPTS / 2];          // 16 KB
    } cp;
    float lbuf[NW][BROWS];         // merge phase (colpack dead)
  } sh;

  int blk = blockIdx.x;            // 0..511
  int mat = blk >> 7;
  int b = (blk >> 4) & 7;
  int rg = blk & 15;
  int tid = threadIdx.x;
  int lane = tid & 63;
  int w = tid >> 6;

  const float4* rowp = (mat == 1 || mat == 3) ? y4 : x4;
  const float4* colp = (mat == 0 || mat == 3) ? y4 : x4;
  int hidx = (mat < 2) ? (mat ^ 1) : mat;
  const float* h = pot_in + (hidx * NB + b) * NPTS;
  const float4* colb = colp + b * NPTS;

  {
    float4 q0 = colb[2 * tid];
    float4 q1 = colb[2 * tid + 1];
    float2 hv = ((const float2*)h)[tid];
    sh.cp.A[tid] = make_float4(q0.x, q1.x, q0.y, q1.y);
    sh.cp.B[tid] = make_float4(q0.z, q1.z, (hv.x - q0.w) * c, (hv.y - q1.w) * c);
  }

  int rowbase = rg * BROWS;
  const float4* rowb = rowp + b * NPTS + rowbase;
  const float* amrow = amax_in + (mat * NB + b) * NPTS + rowbase;

  v2f xs0[R], xs1[R], xs2[R], mref2[R], acc[R];
#pragma unroll
  for (int r = 0; r < R; ++r) {
    float4 p = rowb[r * 64 + lane];
    float a0 = p.x * c, a1 = p.y * c, a2 = p.z * c;
    xs0[r] = (v2f){a0, a0};
    xs1[r] = (v2f){a1, a1};
    xs2[r] = (v2f){a2, a2};
    float mr = amrow[r * 64 + lane] * c;
    mref2[r] = (v2f){mr, mr};
    acc[r] = (v2f){0.0f, 0.0f};
  }
  __syncthreads();

  int p0 = w * CPAIR;
  for (int tp = 0; tp < CPAIR; tp += 4) {   // 4 pairs = 8 cols per iter
    float4 A[4], B[4];
#pragma unroll
    for (int j = 0; j < 4; ++j) {
      A[j] = sh.cp.A[p0 + tp + j];
      B[j] = sh.cp.B[p0 + tp + j];
    }
#pragma unroll
    for (int r = 0; r < R; ++r) {
#pragma unroll
      for (int j = 0; j < 4; ++j) {
        v2f qx = {A[j].x, A[j].y};
        v2f qy = {A[j].z, A[j].w};
        v2f qz = {B[j].x, B[j].y};
        v2f qw = {B[j].z, B[j].w};
        v2f s2 = fma2(xs0[r], qx, fma2(xs1[r], qy, fma2(xs2[r], qz, qw)));
        v2f d = s2 - mref2[r];
        v2f e;
        e.x = wexp2(d.x);
        e.y = wexp2(d.y);
        acc[r] += e;
      }
    }
  }

  __syncthreads();  // colpack dead; safe to overwrite (union)
#pragma unroll
  for (int r = 0; r < R; ++r)
    sh.lbuf[w][r * 64 + lane] = acc[r].x + acc[r].y;
  __syncthreads();

  if (w < 2) {
    int row = w * 64 + lane;       // 0..127
    float L = sh.lbuf[0][row];
#pragma unroll
    for (int q = 1; q < NW; ++q) L += sh.lbuf[q][row];
    float mr = amrow[row] * c;
    float lse = mr + log2f(L);
    float pw = rowb[row].w;
    float res = pw + neg_eps_ln2 * lse + eps_logM;
    float invc = -neg_eps_ln2;
    if (FINAL) {
      float sign = (mat < 2) ? 1.0f : -1.0f;
      float val = sign * res * (1.0f / (float)(NB * NPTS));
#pragma unroll
      for (int off = 32; off; off >>= 1) val += __shfl_xor(val, off);
      if (lane == 0) atomicAdd(out, val);
    } else {
      amax_out[(mat * NB + b) * NPTS + rowbase + row] = lse * invc;
      const float* oldp = pot_in + (mat * NB + b) * NPTS + rowbase;
      float* outp = pot_out + (mat * NB + b) * NPTS + rowbase;
      outp[row] = 0.5f * (oldp[row] + res);
    }
  }
}

// ---------------------------------------------------------------------------
extern "C" void kernel_launch(void* const* d_in, const int* in_sizes, int n_in,
                              void* d_out, int out_size, void* d_ws, size_t ws_size,
                              hipStream_t stream) {
  const float* x = (const float*)d_in[0];
  const float* y = (const float*)d_in[1];
  float* out = (float*)d_out;

  char* ws = (char*)d_ws;
  float4* x4 = (float4*)ws;                        // 256 KB
  float4* y4 = (float4*)(ws + 262144);             // 256 KB
  float* pot = (float*)(ws + 524288);              // 2 * 65536 floats = 512 KB
  float* amax = (float*)(ws + 1048576);            // 65536 floats = 256 KB

  emd_init<<<256, 256, 0, stream>>>(x, y, x4, y4, pot, out);

  // eps schedule: s=8.0, *=0.9 while s>0.01; eps = f32(s)^2; append 0.01^2
  float eps_arr[80];
  int ne = 0;
  double s = 8.0;
  while (s > 0.01) {
    float sf = (float)s;
    eps_arr[ne++] = sf * sf;
    s *= 0.9;
  }
  {
    float bf = 0.01f;
    eps_arr[ne++] = bf * bf;
  }

  const double LOG2E = 1.4426950408889634;
  const double LN2 = 0.6931471805599453;
  const double LOG2048 = 7.624618986159398;

  int cur = 0;
  for (int k = 0; k < ne; ++k) {
    float eps = eps_arr[k];
    float c = (float)(LOG2E / (double)eps);
    float nel = (float)(-(double)eps * LN2);
    float elM = (float)((double)eps * LOG2048);
    if (k == 0) {
      emd_sweep_boot<<<512, 1024, 0, stream>>>(x4, y4, pot + cur * 65536,
                                               pot + (1 - cur) * 65536, amax,
                                               c, nel, elM);
    } else {
      emd_sweep_ref<false><<<512, 1024, 0, stream>>>(
          x4, y4, pot + cur * 65536, pot + (1 - cur) * 65536, amax, amax, out,
          c, nel, elM);
    }
    cur ^= 1;
  }

  {
    float eps = eps_arr[ne - 1];
    float c = (float)(LOG2E / (double)eps);
    float nel = (float)(-(double)eps * LN2);
    float elM = (float)((double)eps * LOG2048);
    emd_sweep_ref<true><<<512, 1024, 0, stream>>>(
        x4, y4, pot + cur * 65536, nullptr, amax, nullptr, out, c, nel, elM);
  }
}